// Round 12
// baseline (43.368 us; speedup 1.0000x reference)
//
#include <hip/hip_runtime.h>
#include <hip/hip_bf16.h>

// Attention: B=4, S=4096, D=64, fp32 in/out, causal + additive padding mask.
// Tier-1 (~16.5 MB ws): prepass -> pre-swizzled bf16 K/V^T 64x64 tiles + mask;
// split-KV flash attention: WG = 128 q-rows x <=6 kv-tiles, 8 waves x 16 q-rows,
// TRIPLE-buffered LDS (single s_barrier/iter, per-wave counted vmcnt, mask
// staged by wave 0), FIXED-MAX softmax, register P-transpose, ones-column
// normalizer. Partials combined by straight summation. Tier-3 fallback kept.

#define S_LEN  4096
#define N_B    4
#define NT64   64                  // S / 64 kv tiles
#define BIGF   1.803368e9f         // (1e10/sqrt(64)) * (1/ln2)
#define QSCALE (0.125f * 1.44269504089f)
#define FIXMAX 11.0f               // fixed softmax offset (log2 units)
#define BIGNEG 1.25e9f             // tier-3: INF / sqrt(64)
#define MADD_PAD 4224

typedef __attribute__((ext_vector_type(8))) short short8;
typedef __attribute__((ext_vector_type(4))) float f32x4;
typedef __attribute__((ext_vector_type(2))) unsigned int uint2v;
typedef unsigned short ushort_t;

// ---------------- tier-1 ws layout (bytes) ----------------
// jobs/batch = 187 (128-row q-blocks T=0..31, v=ceil((2T+2)/6) chunks of <=6
// 64-kv tiles); multi-chunk jobs = 184/batch -> slots = 184*8 waves
#define KT2_OFF   0
#define KT2_BYTES (N_B * NT64 * 4096 * 2)         // 2 MB  [b][t][64 k][64 d swz] bf16
#define VT2_OFF   (KT2_OFF + KT2_BYTES)
#define VT2_BYTES (N_B * NT64 * 4096 * 2)         // 2 MB  [b][t][64 d][64 k swz] bf16
#define NSLOT     (N_B * 184 * 8)                 // 5888
#define OP_OFF    (VT2_OFF + VT2_BYTES)
#define OP_BYTES  (NSLOT * 512 * 4)               // 12.06 MB: [slot][64 d][8 qpair] u32
#define PLS_OFF   (OP_OFF + OP_BYTES)
#define PLS_BYTES (NSLOT * 16 * 4)
#define MADD_OFF  (PLS_OFF + PLS_BYTES)
#define MADD_BYTES (N_B * MADD_PAD * 4)
#define WS8_NEEDED (MADD_OFF + MADD_BYTES)        // ~16.5 MB

__device__ __forceinline__ unsigned short f2bf(float f) {
    union { float f; unsigned u; } v; v.f = f;
    unsigned r = v.u + 0x7FFF + ((v.u >> 16) & 1);   // RNE
    return (unsigned short)(r >> 16);
}
__device__ __forceinline__ float bflo(unsigned u) {
    union { unsigned u; float f; } v; v.u = u << 16; return v.f;
}
__device__ __forceinline__ float bfhi(unsigned u) {
    union { unsigned u; float f; } v; v.u = u & 0xffff0000u; return v.f;
}
__device__ __forceinline__ void ld_lds16(const void* g, void* l) {
    __builtin_amdgcn_global_load_lds((const __attribute__((address_space(1))) void*)g,
                                     (__attribute__((address_space(3))) void*)l, 16, 0, 0);
}
__device__ __forceinline__ void ld_lds4(const void* g, void* l) {
    __builtin_amdgcn_global_load_lds((const __attribute__((address_space(1))) void*)g,
                                     (__attribute__((address_space(3))) void*)l, 4, 0, 0);
}

// =================== tier-1 kernels ===================

// Prepass over 64-kv tiles:
// K  -> bf16 [b][t][64 rows][8x16B chunks, chunk c at c^(row&7)]
// V^T-> bf16 [b][t][64 d  ][8x16B chunks, chunk c at c^(d&7)]
// mask -> additive pre-scaled fp32 (0 when mask==1).
__global__ __launch_bounds__(256)
void prep6(const float* __restrict__ K, const float* __restrict__ V,
           const float* __restrict__ M,
           ushort_t* __restrict__ Kt, ushort_t* __restrict__ Vt,
           float* __restrict__ Madd)
{
    const int t = blockIdx.x, b = blockIdx.y, tid = threadIdx.x;
    ushort_t* ko = Kt + ((size_t)(b * NT64 + t)) * 4096;
    ushort_t* vo = Vt + ((size_t)(b * NT64 + t)) * 4096;
    #pragma unroll
    for (int i = 0; i < 2; ++i) {
        const int idx = tid + 256 * i;
        const int row = idx >> 3, cc = idx & 7;
        const float* src = K + ((size_t)(b * S_LEN + t * 64 + row)) * 64 + cc * 8;
        const f32x4 a = *(const f32x4*)src;
        const f32x4 d4 = *(const f32x4*)(src + 4);
        short8 w;
        w[0]=(short)f2bf(a[0]); w[1]=(short)f2bf(a[1]); w[2]=(short)f2bf(a[2]); w[3]=(short)f2bf(a[3]);
        w[4]=(short)f2bf(d4[0]); w[5]=(short)f2bf(d4[1]); w[6]=(short)f2bf(d4[2]); w[7]=(short)f2bf(d4[3]);
        *(short8*)(ko + row * 64 + ((cc ^ (row & 7)) << 3)) = w;
    }
    #pragma unroll
    for (int i = 0; i < 2; ++i) {
        const int idx = tid + 256 * i;
        const int cc = idx >> 6, d = idx & 63;    // cc = kv chunk (8 k's)
        short8 w;
        #pragma unroll
        for (int j = 0; j < 8; ++j)
            w[j] = (short)f2bf(V[((size_t)(b * S_LEN + t * 64 + cc * 8 + j)) * 64 + d]);
        *(short8*)(vo + d * 64 + ((cc ^ (d & 7)) << 3)) = w;
    }
    if (tid < 64) {
        const int k = t * 64 + tid;
        Madd[b * MADD_PAD + k] = (1.0f - M[b * S_LEN + k]) * BIGF;
    }
}

// register P-transpose: D-layout (p per kv-row group) -> A-fragment
#define PTRANS(PA, PB, PF) do {                                                     \
    unsigned c00_, c01_, c10_, c11_;                                                \
    __asm__("v_cvt_pk_bf16_f32 %0, %1, %2" : "=v"(c00_) : "v"(PA[0]), "v"(PA[1])); \
    __asm__("v_cvt_pk_bf16_f32 %0, %1, %2" : "=v"(c01_) : "v"(PA[2]), "v"(PA[3])); \
    __asm__("v_cvt_pk_bf16_f32 %0, %1, %2" : "=v"(c10_) : "v"(PB[0]), "v"(PB[1])); \
    __asm__("v_cvt_pk_bf16_f32 %0, %1, %2" : "=v"(c11_) : "v"(PB[2]), "v"(PB[3])); \
    uint2v s0_ = __builtin_amdgcn_permlane32_swap(c00_, c10_, false, false);        \
    uint2v s1_ = __builtin_amdgcn_permlane32_swap(c01_, c11_, false, false);        \
    const unsigned T0_ = (unsigned)__builtin_amdgcn_ds_swizzle((int)s0_.x, 0x401F); \
    const unsigned T1_ = (unsigned)__builtin_amdgcn_ds_swizzle((int)s1_.x, 0x401F); \
    const unsigned U0_ = (unsigned)__builtin_amdgcn_ds_swizzle((int)s0_.y, 0x401F); \
    const unsigned U1_ = (unsigned)__builtin_amdgcn_ds_swizzle((int)s1_.y, 0x401F); \
    union { unsigned u[4]; short8 s; } pw_;                                         \
    pw_.u[0] = evn ? s0_.x : U0_;                                                   \
    pw_.u[1] = evn ? s1_.x : U1_;                                                   \
    pw_.u[2] = evn ? T0_ : s0_.y;                                                   \
    pw_.u[3] = evn ? T1_ : s1_.y;                                                   \
    PF = pw_.s;                                                                     \
} while (0)

#define CMASK(SV, BB, QG) do {                     \
    _Pragma("unroll")                              \
    for (int r_ = 0; r_ < 4; ++r_)                 \
        if ((BB) + r_ > (QG)) SV[r_] -= BIGF;      \
} while (0)

// 8-wave WG flash kernel: WG job = (128-row q-block T, chunk c of <=6 64-kv tiles).
// Wave w owns 16 q-rows [128T+16w, +16). Triple-buffered LDS, single barrier
// per iter: wait own-vmcnt ; s_barrier ; stage(t+2) ; compute(t).
__global__ __launch_bounds__(512, 6)
void attn_fa11(const float* __restrict__ Q, const ushort_t* __restrict__ Kt,
               const ushort_t* __restrict__ Vt, const float* __restrict__ Madd,
               unsigned* __restrict__ Opu, float* __restrict__ Pll,
               float* __restrict__ O)
{
    const int x = 186 - blockIdx.x;              // longest jobs first
    const int b = blockIdx.y;
    int v = 1;
    #pragma unroll
    for (int vv = 2; vv <= 11; ++vv) v += (x >= (3 * vv * (vv - 1)) / 2) ? 1 : 0;
    const int y  = x - (3 * v * (v - 1)) / 2;
    const int T  = 3 * (v - 1) + y / v;
    const int c  = y - (y / v) * v;
    const int nt = 2 * T + 2;
    const int t0 = 6 * c;
    const int t1 = (t0 + 6 < nt) ? t0 + 6 : nt;

    const int wid  = threadIdx.x >> 6;           // 0..7
    const int lane = threadIdx.x & 63, l15 = lane & 15, g = lane >> 4;
    const bool evn = ((lane & 16) == 0);
    const int qbase = T * 128 + wid * 16;
    const int dtile = 2 * T + (wid >> 2);        // wave's diagonal 64-kv tile
    const int qg = 16 * (wid & 3) + l15 - 4 * g; // causal threshold within dtile

    __shared__ __attribute__((aligned(16))) ushort_t Kb[3][4096];   // 3 x 8 KB
    __shared__ __attribute__((aligned(16))) ushort_t Vb[3][4096];   // 3 x 8 KB
    __shared__ __attribute__((aligned(16))) float    Ml[3][64];     // 768 B

    // Q as B-fragment (n = l15 = q row, k = g*8+j), scale+1/ln2 folded
    const float* Qrow = Q + ((size_t)(b * S_LEN + qbase + l15)) * 64 + g * 8;
    const f32x4 qa  = *(const f32x4*)(Qrow);
    const f32x4 qb_ = *(const f32x4*)(Qrow + 4);
    const f32x4 qc  = *(const f32x4*)(Qrow + 32);
    const f32x4 qd  = *(const f32x4*)(Qrow + 36);
    short8 qf0, qf1;
    #pragma unroll
    for (int j = 0; j < 4; ++j) {
        qf0[j]     = (short)f2bf(qa[j]  * QSCALE);
        qf0[4 + j] = (short)f2bf(qb_[j] * QSCALE);
        qf1[j]     = (short)f2bf(qc[j]  * QSCALE);
        qf1[4 + j] = (short)f2bf(qd[j]  * QSCALE);
    }
    short8 ones8;
    #pragma unroll
    for (int j = 0; j < 8; ++j) ones8[j] = (short)0x3F80;   // bf16 1.0

    const char*  KtB  = (const char*)Kt + (size_t)b * (NT64 * 8192);
    const char*  VtB  = (const char*)Vt + (size_t)b * (NT64 * 8192);
    const float* MaBs = Madd + (size_t)b * MADD_PAD;

    f32x4 acc[5];
    #pragma unroll
    for (int dt = 0; dt < 5; ++dt) acc[dt] = (f32x4){0.f, 0.f, 0.f, 0.f};

    auto stage = [&](int sl, int t_) {           // 2 vmem events/wave (3 for wave 0)
        ld_lds16(KtB + (size_t)t_ * 8192 + wid * 1024 + lane * 16,
                 (char*)&Kb[sl][0] + wid * 1024);
        ld_lds16(VtB + (size_t)t_ * 8192 + wid * 1024 + lane * 16,
                 (char*)&Vb[sl][0] + wid * 1024);
        if (wid == 0)
            ld_lds4(MaBs + (size_t)t_ * 64 + lane, &Ml[sl][0]);
    };

    stage(0, t0);
    if (t0 + 1 < t1) stage(1, t0 + 1);

    const int ch0 = ((g ^ (l15 & 7)) << 3);           // chunk g     (k 0..31)
    const int ch1 = (((4 | g) ^ (l15 & 7)) << 3);     // chunk 4+g   (k 32..63)

    int sc = 0;                                   // slot of current tile
    for (int t = t0; t < t1; ++t) {
        if (t + 1 < t1) {
            if (wid == 0) __asm__ volatile("s_waitcnt vmcnt(3)" ::: "memory");
            else          __asm__ volatile("s_waitcnt vmcnt(2)" ::: "memory");
        } else {
            __asm__ volatile("s_waitcnt vmcnt(0)" ::: "memory");
        }
        __builtin_amdgcn_s_barrier();             // all eighths of tile t ready
        __builtin_amdgcn_sched_barrier(0);

        const int sn = (sc + 2 > 2) ? sc - 1 : sc + 2;   // (sc+2)%3
        if (t + 2 < t1) stage(sn, t + 2);         // overwrites slot of t-1 (safe)

        if (t <= dtile) {
            const ushort_t* kb  = &Kb[sc][0];
            const ushort_t* vb  = &Vb[sc][0];
            const float*    mlw = &Ml[sc][0];
            const f32x4 z_ = (f32x4){0.f, 0.f, 0.f, 0.f};

            short8 k00 = *(const short8*)(kb + ((0  + l15) << 6) + ch0);
            short8 k01 = *(const short8*)(kb + ((0  + l15) << 6) + ch1);
            short8 k10 = *(const short8*)(kb + ((16 + l15) << 6) + ch0);
            short8 k11 = *(const short8*)(kb + ((16 + l15) << 6) + ch1);
            short8 k20 = *(const short8*)(kb + ((32 + l15) << 6) + ch0);
            short8 k21 = *(const short8*)(kb + ((32 + l15) << 6) + ch1);
            short8 k30 = *(const short8*)(kb + ((48 + l15) << 6) + ch0);
            short8 k31 = *(const short8*)(kb + ((48 + l15) << 6) + ch1);
            f32x4 st0 = __builtin_amdgcn_mfma_f32_16x16x32_bf16(k00, qf0, z_, 0, 0, 0);
            f32x4 st1 = __builtin_amdgcn_mfma_f32_16x16x32_bf16(k10, qf0, z_, 0, 0, 0);
            f32x4 st2 = __builtin_amdgcn_mfma_f32_16x16x32_bf16(k20, qf0, z_, 0, 0, 0);
            f32x4 st3 = __builtin_amdgcn_mfma_f32_16x16x32_bf16(k30, qf0, z_, 0, 0, 0);
            st0 = __builtin_amdgcn_mfma_f32_16x16x32_bf16(k01, qf1, st0, 0, 0, 0);
            st1 = __builtin_amdgcn_mfma_f32_16x16x32_bf16(k11, qf1, st1, 0, 0, 0);
            st2 = __builtin_amdgcn_mfma_f32_16x16x32_bf16(k21, qf1, st2, 0, 0, 0);
            st3 = __builtin_amdgcn_mfma_f32_16x16x32_bf16(k31, qf1, st3, 0, 0, 0);

            st0 -= *(const f32x4*)(mlw + 4 * g);
            st1 -= *(const f32x4*)(mlw + 16 + 4 * g);
            st2 -= *(const f32x4*)(mlw + 32 + 4 * g);
            st3 -= *(const f32x4*)(mlw + 48 + 4 * g);
            if (t == dtile) {
                CMASK(st0, 0, qg);  CMASK(st1, 16, qg);
                CMASK(st2, 32, qg); CMASK(st3, 48, qg);
            }

            float p0[4], p1[4], p2[4], p3[4];
            #pragma unroll
            for (int r = 0; r < 4; ++r) {
                p0[r] = exp2f(st0[r] - FIXMAX);
                p1[r] = exp2f(st1[r] - FIXMAX);
                p2[r] = exp2f(st2[r] - FIXMAX);
                p3[r] = exp2f(st3[r] - FIXMAX);
            }

            short8 pfA, pfB;
            PTRANS(p0, p1, pfA);                  // kv 0..31
            PTRANS(p2, p3, pfB);                  // kv 32..63

            short8 vA0 = *(const short8*)(vb + ((0  + l15) << 6) + ch0);
            short8 vB0 = *(const short8*)(vb + ((0  + l15) << 6) + ch1);
            short8 vA1 = *(const short8*)(vb + ((16 + l15) << 6) + ch0);
            short8 vB1 = *(const short8*)(vb + ((16 + l15) << 6) + ch1);
            short8 vA2 = *(const short8*)(vb + ((32 + l15) << 6) + ch0);
            short8 vB2 = *(const short8*)(vb + ((32 + l15) << 6) + ch1);
            short8 vA3 = *(const short8*)(vb + ((48 + l15) << 6) + ch0);
            short8 vB3 = *(const short8*)(vb + ((48 + l15) << 6) + ch1);
            __builtin_amdgcn_s_setprio(1);
            acc[0] = __builtin_amdgcn_mfma_f32_16x16x32_bf16(pfA, vA0, acc[0], 0, 0, 0);
            acc[1] = __builtin_amdgcn_mfma_f32_16x16x32_bf16(pfA, vA1, acc[1], 0, 0, 0);
            acc[2] = __builtin_amdgcn_mfma_f32_16x16x32_bf16(pfA, vA2, acc[2], 0, 0, 0);
            acc[3] = __builtin_amdgcn_mfma_f32_16x16x32_bf16(pfA, vA3, acc[3], 0, 0, 0);
            acc[4] = __builtin_amdgcn_mfma_f32_16x16x32_bf16(pfA, ones8, acc[4], 0, 0, 0);
            acc[0] = __builtin_amdgcn_mfma_f32_16x16x32_bf16(pfB, vB0, acc[0], 0, 0, 0);
            acc[1] = __builtin_amdgcn_mfma_f32_16x16x32_bf16(pfB, vB1, acc[1], 0, 0, 0);
            acc[2] = __builtin_amdgcn_mfma_f32_16x16x32_bf16(pfB, vB2, acc[2], 0, 0, 0);
            acc[3] = __builtin_amdgcn_mfma_f32_16x16x32_bf16(pfB, vB3, acc[3], 0, 0, 0);
            acc[4] = __builtin_amdgcn_mfma_f32_16x16x32_bf16(pfB, ones8, acc[4], 0, 0, 0);
            __builtin_amdgcn_s_setprio(0);
        }
        sc = (sc == 2) ? 0 : sc + 1;
    }

    if (v == 1) {
        // single chunk (T < 3): final O; normalizer = ones-column acc
        float* Ob = O + ((size_t)(b * S_LEN + qbase)) * 64;
        #pragma unroll
        for (int r = 0; r < 4; ++r) {
            const float il = 1.0f / acc[4][r];
            #pragma unroll
            for (int dt = 0; dt < 4; ++dt)
                Ob[(4 * g + r) * 64 + 16 * dt + l15] = acc[dt][r] * il;
        }
    } else {
        // partial: bf16 O pairs [d=64][qpair=8]
        const int slot = (b * 184 + (x - 3)) * 8 + wid;
        unsigned* Os = Opu + (size_t)slot * 512;
        #pragma unroll
        for (int dt = 0; dt < 4; ++dt) {
            unsigned plo, phi;
            __asm__("v_cvt_pk_bf16_f32 %0, %1, %2" : "=v"(plo) : "v"(acc[dt][0]), "v"(acc[dt][1]));
            __asm__("v_cvt_pk_bf16_f32 %0, %1, %2" : "=v"(phi) : "v"(acc[dt][2]), "v"(acc[dt][3]));
            *(uint2v*)&Os[(16 * dt + l15) * 8 + g * 2] = (uint2v){plo, phi};
        }
        if (l15 == 0) {
            #pragma unroll
            for (int r = 0; r < 4; ++r)
                Pll[slot * 16 + 4 * g + r] = acc[4][r];
        }
    }
}

// Merge partials for blocks T in [3, 32): straight sums (fixed-max).
// One WG per (block T, wave slot wv): 16 rows x 64 d.
__global__ __launch_bounds__(256)
void combine7(const unsigned* __restrict__ Opu, const float* __restrict__ Pll,
              float* __restrict__ O)
{
    const int bx = blockIdx.x, b = blockIdx.y;   // bx in [0, 232)
    const int T = 3 + (bx >> 3), wv = bx & 7;
    const int v = (T + 3) / 3;                   // ceil((2T+2)/6)
    const int x0 = (3 * v * (v - 1)) / 2 + (T - 3 * (v - 1)) * v;
    const int sb = (b * 184 + (x0 - 3)) * 8 + wv;
    const int tid = threadIdx.x, rg = tid >> 6, d = tid & 63;   // rows 4rg..4rg+3

    float l[4] = {0.f, 0.f, 0.f, 0.f};
    float a[4] = {0.f, 0.f, 0.f, 0.f};
    for (int cc = 0; cc < v; ++cc) {
        const int sl = sb + 8 * cc;
        const uint2v pu = *(const uint2v*)&Opu[(size_t)sl * 512 + d * 8 + rg * 2];
        a[0] += bflo(pu[0]);
        a[1] += bfhi(pu[0]);
        a[2] += bflo(pu[1]);
        a[3] += bfhi(pu[1]);
        #pragma unroll
        for (int j = 0; j < 4; ++j)
            l[j] += Pll[sl * 16 + 4 * rg + j];
    }
    float* Ob = O + ((size_t)(b * S_LEN + T * 128 + wv * 16 + 4 * rg)) * 64 + d;
    #pragma unroll
    for (int j = 0; j < 4; ++j)
        Ob[(size_t)j * 64] = a[j] / l[j];
}

// =================== tier-3 fallback (no ws) ===================

__global__ __launch_bounds__(256)
void attn_fwd_fb(const float* __restrict__ Q, const float* __restrict__ K,
                 const float* __restrict__ V, const float* __restrict__ M,
                 float* __restrict__ O)
{
    const int tile  = blockIdx.x;
    const int b     = blockIdx.y;
    const int qbase = tile * 64;
    const int tid   = threadIdx.x;
    const int wave  = tid >> 6;
    const int lane  = tid & 63;
    const int l15   = lane & 15;
    const int g     = lane >> 4;

    __shared__ __attribute__((aligned(16))) unsigned short Klds[32 * 64];
    __shared__ __attribute__((aligned(16))) unsigned short Vtlds[64 * 40];
    __shared__ __attribute__((aligned(16))) unsigned short Plds[4][16 * 40];

    const float* Qb = Q + ((size_t)b * S_LEN + qbase) * 64;
    const float* Kb = K + (size_t)b * S_LEN * 64;
    const float* Vb = V + (size_t)b * S_LEN * 64;
    const float* Mb = M + (size_t)b * S_LEN;

    const int qrow = 16 * wave + l15;
    short8 qf[2];
    #pragma unroll
    for (int dc = 0; dc < 2; ++dc) {
        const float* src = Qb + (size_t)qrow * 64 + dc * 32 + g * 8;
        #pragma unroll
        for (int j = 0; j < 8; ++j) qf[dc][j] = (short)f2bf(src[j] * 0.125f);
    }

    f32x4 acc[4];
    #pragma unroll
    for (int dt = 0; dt < 4; ++dt) acc[dt] = (f32x4){0.f, 0.f, 0.f, 0.f};
    float mrow[4], lrow[4];
    #pragma unroll
    for (int r = 0; r < 4; ++r) { mrow[r] = -1e30f; lrow[r] = 0.f; }

    const int q_max_wave = qbase + 16 * wave + 15;
    const int nkv = (qbase + 64) / 32;

    for (int it = 0; it < nkv; ++it) {
        const int kv = it * 32;
        __syncthreads();
        {
            const int k = tid >> 3, c = tid & 7;
            const float* src = Kb + (size_t)(kv + k) * 64 + c * 8;
            short8 t8;
            #pragma unroll
            for (int j = 0; j < 8; ++j) t8[j] = (short)f2bf(src[j]);
            const int byte = k * 128 + ((c * 16) ^ ((k & 7) << 4));
            *(short8*)((char*)Klds + byte) = t8;
        }
        {
            const int k = tid & 31, dch = tid >> 5;
            const float* src = Vb + (size_t)(kv + k) * 64 + dch * 8;
            #pragma unroll
            for (int j = 0; j < 8; ++j)
                Vtlds[(dch * 8 + j) * 40 + k] = f2bf(src[j]);
        }
        __syncthreads();

        if (kv > q_max_wave) continue;

        f32x4 s[2];
        s[0] = (f32x4){0.f,0.f,0.f,0.f};
        s[1] = (f32x4){0.f,0.f,0.f,0.f};
        #pragma unroll
        for (int kt = 0; kt < 2; ++kt) {
            const int krow = 16 * kt + l15;
            #pragma unroll
            for (int dc = 0; dc < 2; ++dc) {
                const int byte = krow * 128 + ((dc * 64 + g * 16) ^ ((krow & 7) << 4));
                short8 kf = *(const short8*)((const char*)Klds + byte);
                s[kt] = __builtin_amdgcn_mfma_f32_16x16x32_bf16(qf[dc], kf, s[kt], 0, 0, 0);
            }
        }

        float mk0 = Mb[kv + l15];
        float mk1 = Mb[kv + 16 + l15];
        #pragma unroll
        for (int kt = 0; kt < 2; ++kt) {
            const int gk = kv + 16 * kt + l15;
            const float madd = (1.0f - (kt ? mk1 : mk0)) * BIGNEG;
            #pragma unroll
            for (int r = 0; r < 4; ++r) {
                const int gq = qbase + 16 * wave + 4 * g + r;
                float vv = s[kt][r] - madd;
                if (gk > gq) vv -= BIGNEG;
                s[kt][r] = vv;
            }
        }

        float pexp[2][4], alpha[4];
        #pragma unroll
        for (int r = 0; r < 4; ++r) {
            float tm = fmaxf(s[0][r], s[1][r]);
            #pragma unroll
            for (int off = 8; off >= 1; off >>= 1)
                tm = fmaxf(tm, __shfl_xor(tm, off, 64));
            const float mnew = fmaxf(mrow[r], tm);
            const float a  = __expf(mrow[r] - mnew);
            const float p0 = __expf(s[0][r] - mnew);
            const float p1 = __expf(s[1][r] - mnew);
            float rs = p0 + p1;
            #pragma unroll
            for (int off = 8; off >= 1; off >>= 1)
                rs += __shfl_xor(rs, off, 64);
            lrow[r] = lrow[r] * a + rs;
            mrow[r] = mnew;
            alpha[r] = a;
            pexp[0][r] = p0; pexp[1][r] = p1;
        }

        #pragma unroll
        for (int dt = 0; dt < 4; ++dt)
            #pragma unroll
            for (int r = 0; r < 4; ++r)
                acc[dt][r] *= alpha[r];

        unsigned short* P = Plds[wave];
        #pragma unroll
        for (int kt = 0; kt < 2; ++kt)
            #pragma unroll
            for (int r = 0; r < 4; ++r)
                P[(4 * g + r) * 40 + 16 * kt + l15] = f2bf(pexp[kt][r]);

        __asm__ volatile("s_waitcnt lgkmcnt(0)" ::: "memory");

        short8 pf = *(const short8*)((const char*)P + (l15 * 40 + g * 8) * 2);
        #pragma unroll
        for (int dt = 0; dt < 4; ++dt) {
            short8 vf = *(const short8*)((const char*)Vtlds + ((dt * 16 + l15) * 40 + g * 8) * 2);
            acc[dt] = __builtin_amdgcn_mfma_f32_16x16x32_bf16(pf, vf, acc[dt], 0, 0, 0);
        }
    }

    float* Ob = O + ((size_t)b * S_LEN + qbase) * 64;
    #pragma unroll
    for (int r = 0; r < 4; ++r) {
        const float inv = 1.0f / lrow[r];
        const int row = 16 * wave + 4 * g + r;
        #pragma unroll
        for (int dt = 0; dt < 4; ++dt)
            Ob[(size_t)row * 64 + dt * 16 + l15] = acc[dt][r] * inv;
    }
}

extern "C" void kernel_launch(void* const* d_in, const int* in_sizes, int n_in,
                              void* d_out, int out_size, void* d_ws, size_t ws_size,
                              hipStream_t stream) {
    const float* Q = (const float*)d_in[0];
    const float* K = (const float*)d_in[1];
    const float* V = (const float*)d_in[2];
    const float* M = (const float*)d_in[3];
    float* O = (float*)d_out;

    if (ws_size >= (size_t)WS8_NEEDED) {
        ushort_t* Kt = (ushort_t*)((char*)d_ws + KT2_OFF);
        ushort_t* Vt = (ushort_t*)((char*)d_ws + VT2_OFF);
        unsigned* Op = (unsigned*)((char*)d_ws + OP_OFF);
        float*    Pll= (float*)((char*)d_ws + PLS_OFF);
        float*    Ma = (float*)((char*)d_ws + MADD_OFF);
        prep6<<<dim3(NT64, N_B), 256, 0, stream>>>(K, V, M, Kt, Vt, Ma);
        attn_fa11<<<dim3(187, N_B), 512, 0, stream>>>(Q, Kt, Vt, Ma, Op, Pll, O);
        combine7<<<dim3(232, N_B), 256, 0, stream>>>(Op, Pll, O);
    } else {
        dim3 grid(S_LEN / 64, N_B);
        attn_fwd_fb<<<grid, 256, 0, stream>>>(Q, K, V, M, O);
    }
}